// Round 18
// baseline (708.653 us; speedup 1.0000x reference)
//
#include <hip/hip_runtime.h>
#include <math.h>

#define N_NODES 30000
#define N_EDGES 480000
#define HEADS   6
#define NN2 (2 * N_NODES)
#define NE2 (2 * N_EDGES)

typedef __attribute__((ext_vector_type(8))) short bf16x8;
typedef __attribute__((ext_vector_type(4))) float f32x4;
typedef __attribute__((ext_vector_type(2))) float f32x2;
typedef __attribute__((ext_vector_type(2))) unsigned u32x2;
typedef __attribute__((ext_vector_type(4))) unsigned u32x4;

// ---------- bf16 helper (agg outputs feeding next GEMM's A-operand) ----------
__device__ __forceinline__ unsigned short f2bf(float f) {
    unsigned u = __float_as_uint(f);
    u += 0x7fffu + ((u >> 16) & 1u);   // RNE
    return (unsigned short)(u >> 16);
}

// ---------- layer-1 GEMM (K=11, VALU) fused with es/ed + fp8-z epilogue (R15) ----------
__global__ void gemm1_es_kernel(const float* __restrict__ x0, const float* __restrict__ x1,
                                const float* __restrict__ W, const float* __restrict__ a_s,
                                const float* __restrict__ a_d,
                                unsigned char* __restrict__ zf8b, float* __restrict__ es_t,
                                float* __restrict__ ed_t) {
    constexpr int K = 11, HF = 96, TM = 16;
    __shared__ float hs[TM * K];
    const int m0 = blockIdx.x * TM;
    const float* h = (m0 < N_NODES) ? (x0 + (size_t)m0 * K)
                                    : (x1 + (size_t)(m0 - N_NODES) * K);
    const int j = blockIdx.y * 64 + threadIdx.x;
    for (int idx = threadIdx.x; idx < TM * K; idx += 64) hs[idx] = h[idx];
    __syncthreads();
    if (j >= HF) return;
    float acc[TM];
#pragma unroll
    for (int m = 0; m < TM; ++m) acc[m] = 0.f;
    for (int k = 0; k < K; ++k) {
        float w = W[k * HF + j];
#pragma unroll
        for (int m = 0; m < TM; ++m) acc[m] = fmaf(hs[m * K + k], w, acc[m]);
    }
    const float as_v = a_s[j];
    const float ad_v = a_d[j];
    const int hh = j >> 4;          // head = col/16 (Fo=16)
#pragma unroll
    for (int m = 0; m < TM; ++m) {
        const int pk = __builtin_amdgcn_cvt_pk_fp8_f32(acc[m], acc[m], 0, false);
        zf8b[(size_t)(m0 + m) * HF + j] = (unsigned char)pk;
    }
#pragma unroll
    for (int m = 0; m < TM; ++m) {
        float ep = acc[m] * as_v;
        float dp = acc[m] * ad_v;
#pragma unroll
        for (int d = 1; d < 16; d <<= 1) {
            ep += __shfl_xor(ep, d);
            dp += __shfl_xor(dp, d);
        }
        if ((threadIdx.x & 15) == 0) {
            es_t[(size_t)hh * NN2 + m0 + m] = ep;
            ed_t[(size_t)hh * NN2 + m0 + m] = dp;
        }
    }
}

// ---------- W -> Wt (transposed, bf16) ----------
__global__ void convert_wt_kernel(const float* __restrict__ W, unsigned short* __restrict__ Wt,
                                  int K, int HF) {
    const int idx = blockIdx.x * 256 + threadIdx.x;
    if (idx >= K * HF) return;
    const int k = idx / HF;
    const int n = idx - k * HF;
    Wt[n * K + k] = f2bf(W[idx]);
}

// ---------- MFMA GEMM fused with es/ed + fp8-z epilogue (R15) ----------
template <int K, int HF>
__global__ __launch_bounds__(256) void gemm_es_kernel(
        const unsigned short* __restrict__ hbf, const unsigned short* __restrict__ Wt,
        const float* __restrict__ a_s, const float* __restrict__ a_d,
        unsigned char* __restrict__ zf8b, float* __restrict__ es_t,
        float* __restrict__ ed_t) {
    constexpr int KSTEPS = K / 32;
    constexpr int Fo  = HF / HEADS;
    constexpr int TPH = Fo / 16;        // tiles per head
    const int wid = blockIdx.x * 4 + (threadIdx.x >> 6);
    if (wid >= NN2 / 16) return;
    const int lane = threadIdx.x & 63;
    const int r16  = lane & 15;
    const int quad = lane >> 4;
    const int m0 = wid * 16;

    bf16x8 afrag[KSTEPS];
    const unsigned short* ap = hbf + (size_t)(m0 + r16) * K + quad * 8;
#pragma unroll
    for (int i = 0; i < KSTEPS; ++i) afrag[i] = *(const bf16x8*)(ap + i * 32);

    const unsigned short* bp = Wt + (size_t)r16 * K + quad * 8;
    float es_p[4] = {0.f, 0.f, 0.f, 0.f};
    float ed_p[4] = {0.f, 0.f, 0.f, 0.f};
    for (int t = 0; t < HF / 16; ++t) {
        f32x4 acc = {0.f, 0.f, 0.f, 0.f};
        const unsigned short* bpt = bp + (size_t)t * 16 * K;
#pragma unroll
        for (int i = 0; i < KSTEPS; ++i) {
            const bf16x8 bfrag = *(const bf16x8*)(bpt + i * 32);
            acc = __builtin_amdgcn_mfma_f32_16x16x32_bf16(afrag[i], bfrag, acc, 0, 0, 0);
        }
        const float as_v = a_s[t * 16 + r16];
        const float ad_v = a_d[t * 16 + r16];
        unsigned char* zp = zf8b + (size_t)(m0 + quad * 4) * HF + t * 16 + r16;
#pragma unroll
        for (int r = 0; r < 4; ++r) {
            const int pk = __builtin_amdgcn_cvt_pk_fp8_f32(acc[r], acc[r], 0, false);
            zp[(size_t)r * HF] = (unsigned char)pk;
            es_p[r] = fmaf(acc[r], as_v, es_p[r]);
            ed_p[r] = fmaf(acc[r], ad_v, ed_p[r]);
        }
        if (((t + 1) % TPH) == 0) {     // head boundary: reduce + store + reset
            const int h = t / TPH;
#pragma unroll
            for (int r = 0; r < 4; ++r) {
                float ep = es_p[r], dp = ed_p[r];
#pragma unroll
                for (int d = 1; d < 16; d <<= 1) {
                    ep += __shfl_xor(ep, d);
                    dp += __shfl_xor(dp, d);
                }
                if (r16 == 0) {
                    es_t[(size_t)h * NN2 + m0 + quad * 4 + r] = ep;
                    ed_t[(size_t)h * NN2 + m0 + quad * 4 + r] = dp;
                }
                es_p[r] = 0.f;
                ed_p[r] = 0.f;
            }
        }
    }
}

// ---------- CSR build (both graphs, global node ids; src stored as u16) ----------
__global__ void zero_int_kernel(int* __restrict__ p, int n) {
    const int i = blockIdx.x * 256 + threadIdx.x;
    if (i < n) p[i] = 0;
}

__global__ void hist2_kernel(const int* __restrict__ ei0, const int* __restrict__ ei1,
                             int* __restrict__ cnt) {
    const int e = blockIdx.x * 256 + threadIdx.x;
    if (e >= NE2) return;
    const int g = e >= N_EDGES;
    const int* ei = g ? ei1 : ei0;
    const int e2 = e - g * N_EDGES;
    atomicAdd(&cnt[g * N_NODES + ei[N_EDGES + e2]], 1);
}

#define SCAN_NB ((NN2 + 1023) / 1024)
__global__ void scan1_kernel(const int* __restrict__ cnt, int* __restrict__ part,
                             int* __restrict__ bsum) {
    __shared__ int s[1024];
    const int t = threadIdx.x;
    const int gid = blockIdx.x * 1024 + t;
    const int v = (gid < NN2) ? cnt[gid] : 0;
    s[t] = v;
    __syncthreads();
    for (int d = 1; d < 1024; d <<= 1) {
        int x = (t >= d) ? s[t - d] : 0;
        __syncthreads();
        s[t] += x;
        __syncthreads();
    }
    part[gid] = s[t] - v;
    if (t == 1023) bsum[blockIdx.x] = s[1023];
}

__global__ void scan2_kernel(int* __restrict__ bsum, int* __restrict__ boff) {
    if (threadIdx.x == 0) {
        int a = 0;
        for (int i = 0; i < SCAN_NB; ++i) { boff[i] = a; a += bsum[i]; }
        boff[SCAN_NB] = a;
    }
}

__global__ void scan3_kernel(const int* __restrict__ part, const int* __restrict__ boff,
                             int* __restrict__ off, int* __restrict__ cursor) {
    const int gid = blockIdx.x * 1024 + threadIdx.x;
    if (gid < NN2) {
        const int o = part[gid] + boff[gid >> 10];
        off[gid] = o;
        cursor[gid] = o;
    }
    if (gid == 0) off[NN2] = boff[SCAN_NB];
}

__global__ void scatter2_kernel(const int* __restrict__ ei0, const int* __restrict__ ei1,
                                int* __restrict__ cursor,
                                unsigned short* __restrict__ csr16) {
    const int e = blockIdx.x * 256 + threadIdx.x;
    if (e >= NE2) return;
    const int g = e >= N_EDGES;
    const int* ei = g ? ei1 : ei0;
    const int e2 = e - g * N_EDGES;
    const int src = g * N_NODES + ei[e2];           // < 60000, fits u16
    const int dst = g * N_NODES + ei[N_EDGES + e2];
    const int slot = atomicAdd(&cursor[dst], 1);
    csr16[slot] = (unsigned short)src;
}

// ---------- layer aggs: sub-wave node-head groups, 8B zf8 loads (EPI=8) ----------
// GS lanes own one (node, head): L=Fo/8 feat-lanes (2 dwords = 8 feats each) x EPI=GS/L
// edges in flight. Reduction: log2(EPI)... d=L..GS/2 within group. Nodes sequential.
// XCD-affine head swizzle, exact coverage: r<6 -> h=r, blk=g (g<MAIN);
// r in {6,7} -> k=(r-6)*G+g, h=k%6, blk=MAIN+k/6 (k < 6*(BPH-MAIN)). Grid = 8*G.
template <int HF, int GS, int MAIN, int G>
__global__ __launch_bounds__(256) void agg_sub_kernel(
        const int* __restrict__ off, const unsigned short* __restrict__ csr16,
        const float* __restrict__ es_t, const float* __restrict__ ed_t,
        const unsigned* __restrict__ zf8, unsigned short* __restrict__ outz) {
    constexpr int Fo  = HF / HEADS;
    constexpr int L   = Fo / 8;          // lanes per edge (8 feats / lane)
    constexpr int EPI = GS / L;          // edges in parallel (8)
    constexpr int GPW = 64 / GS;         // node-heads per wave
    constexpr int NB  = 4 * GPW;         // node-heads per block
    constexpr int BPH = NN2 / NB;        // blocks per head
    int h, blk;
    {
        const int r = blockIdx.x & 7, g = blockIdx.x >> 3;
        if (r < 6) {
            if (g >= MAIN) return;
            h = r; blk = g;
        } else {
            const int k = (r - 6) * G + g;
            if (k >= 6 * (BPH - MAIN)) return;
            h = k % 6; blk = MAIN + k / 6;
        }
    }
    const int wavid = threadIdx.x >> 6;
    const int lane  = threadIdx.x & 63;
    const int grp = lane / GS;           // node-head group within wave
    const int lg  = lane - grp * GS;
    const int eo = lg / L;
    const int fp = lg - eo * L;
    const int n = blk * NB + wavid * GPW + grp;

    const int s0  = off[n];
    const int deg = off[n + 1] - s0;
    const float edn = ed_t[(size_t)h * NN2 + n];
    const float* esh = es_t + (size_t)h * NN2;
    const unsigned* zbase = zf8 + h * (Fo / 4) + 2 * fp;

    float a[8] = {0.f, 0.f, 0.f, 0.f, 0.f, 0.f, 0.f, 0.f};
    float lsum = 0.f;
#pragma unroll 4
    for (int i = eo; i < deg; i += EPI) {
        const int src = (int)csr16[s0 + i];
        float v = esh[src] + edn;
        v = fmaxf(v, 0.2f * v);
        const float ww = __expf(v);
        lsum += ww;
        const u32x2 zz = *(const u32x2*)(zbase + (size_t)src * (HF / 4));
        const f32x2 lo0 = __builtin_amdgcn_cvt_pk_f32_fp8((int)zz.x, false);
        const f32x2 hi0 = __builtin_amdgcn_cvt_pk_f32_fp8((int)zz.x, true);
        const f32x2 lo1 = __builtin_amdgcn_cvt_pk_f32_fp8((int)zz.y, false);
        const f32x2 hi1 = __builtin_amdgcn_cvt_pk_f32_fp8((int)zz.y, true);
        a[0] = fmaf(ww, lo0.x, a[0]);
        a[1] = fmaf(ww, lo0.y, a[1]);
        a[2] = fmaf(ww, hi0.x, a[2]);
        a[3] = fmaf(ww, hi0.y, a[3]);
        a[4] = fmaf(ww, lo1.x, a[4]);
        a[5] = fmaf(ww, lo1.y, a[5]);
        a[6] = fmaf(ww, hi1.x, a[6]);
        a[7] = fmaf(ww, hi1.y, a[7]);
    }
#pragma unroll
    for (int d = L; d < GS; d <<= 1) {   // reduce within GS-group only
#pragma unroll
        for (int j = 0; j < 8; ++j) a[j] += __shfl_xor(a[j], d);
        lsum += __shfl_xor(lsum, d);
    }
    if (eo == 0) {
        const float inv = 1.f / (lsum + 1e-16f);
        unsigned pk[4];
#pragma unroll
        for (int j = 0; j < 4; ++j) {
            float o0 = a[2 * j] * inv, o1 = a[2 * j + 1] * inv;
            o0 = o0 > 0.f ? o0 : expm1f(o0);
            o1 = o1 > 0.f ? o1 : expm1f(o1);
            pk[j] = (unsigned)f2bf(o0) | ((unsigned)f2bf(o1) << 16);
        }
        u32x4 v4 = {pk[0], pk[1], pk[2], pk[3]};
        *(u32x4*)(outz + (size_t)n * HF + h * Fo + 8 * fp) = v4;   // 16B store
    }
}

// ---------- layer-3 aggregation fused with sum pooling, 8B zf8 loads (EPI=8) ----------
#define POOL_BLOCKS 3072
#define POOL_WPH 2048
__global__ __launch_bounds__(256) void agg_pool_kernel(
        const int* __restrict__ off, const unsigned short* __restrict__ csr16,
        const float* __restrict__ es_t, const float* __restrict__ ed_t,
        const unsigned* __restrict__ zf8, float* __restrict__ pooled) {
    constexpr int HF = 384, Fo = 64, L = 8, EPI = 8;
    __shared__ float lds[128];
    int h, slot;
    {
        const int r = blockIdx.x & 7, g = blockIdx.x >> 3;   // g in [0,384)
        if (r < 6) { h = r; slot = g; }
        else { h = g % 6; slot = 384 + (r - 6) * 64 + g / 6; }
    }
    const int wavid = threadIdx.x >> 6;
    const int ws    = slot * 4 + wavid;
    const int lane  = threadIdx.x & 63;
    const int eo = lane / L;
    const int fp = lane - eo * L;
    const float* esh = es_t + (size_t)h * NN2;
    const float* edh = ed_t + (size_t)h * NN2;
    const unsigned* zbase = zf8 + h * (Fo / 4) + 2 * fp;

    if (threadIdx.x < 128) lds[threadIdx.x] = 0.f;
    __syncthreads();

    float p0[8] = {0.f, 0.f, 0.f, 0.f, 0.f, 0.f, 0.f, 0.f};
    float p1[8] = {0.f, 0.f, 0.f, 0.f, 0.f, 0.f, 0.f, 0.f};
    for (int n = ws; n < NN2; n += POOL_WPH) {
        const int s0  = off[n];
        const int deg = off[n + 1] - s0;
        const float edn = edh[n];
        float a[8] = {0.f, 0.f, 0.f, 0.f, 0.f, 0.f, 0.f, 0.f};
        float lsum = 0.f;
#pragma unroll 4
        for (int i = eo; i < deg; i += EPI) {
            const int src = (int)csr16[s0 + i];
            float v = esh[src] + edn;
            v = fmaxf(v, 0.2f * v);
            const float ww = __expf(v);
            lsum += ww;
            const u32x2 zz = *(const u32x2*)(zbase + (size_t)src * (HF / 4));
            const f32x2 lo0 = __builtin_amdgcn_cvt_pk_f32_fp8((int)zz.x, false);
            const f32x2 hi0 = __builtin_amdgcn_cvt_pk_f32_fp8((int)zz.x, true);
            const f32x2 lo1 = __builtin_amdgcn_cvt_pk_f32_fp8((int)zz.y, false);
            const f32x2 hi1 = __builtin_amdgcn_cvt_pk_f32_fp8((int)zz.y, true);
            a[0] = fmaf(ww, lo0.x, a[0]);
            a[1] = fmaf(ww, lo0.y, a[1]);
            a[2] = fmaf(ww, hi0.x, a[2]);
            a[3] = fmaf(ww, hi0.y, a[3]);
            a[4] = fmaf(ww, lo1.x, a[4]);
            a[5] = fmaf(ww, lo1.y, a[5]);
            a[6] = fmaf(ww, hi1.x, a[6]);
            a[7] = fmaf(ww, hi1.y, a[7]);
        }
#pragma unroll
        for (int d = L; d < 64; d <<= 1) {
#pragma unroll
            for (int j = 0; j < 8; ++j) a[j] += __shfl_xor(a[j], d);
            lsum += __shfl_xor(lsum, d);
        }
        if (eo == 0) {
            const float inv = 1.f / (lsum + 1e-16f);
            float* p = (n < N_NODES) ? p0 : p1;
#pragma unroll
            for (int j = 0; j < 8; ++j) {
                float o = a[j] * inv;
                o = o > 0.f ? o : expm1f(o);
                p[j] += o;
            }
        }
    }
    if (eo == 0) {
#pragma unroll
        for (int j = 0; j < 8; ++j) {
            atomicAdd(&lds[8 * fp + j], p0[j]);
            atomicAdd(&lds[64 + 8 * fp + j], p1[j]);
        }
    }
    __syncthreads();
    if (threadIdx.x < 128) {
        const int g2 = threadIdx.x >> 6;
        const int f  = threadIdx.x & 63;
        atomicAdd(&pooled[g2 * 384 + h * Fo + f], lds[threadIdx.x]);
    }
}

__global__ void zero_pooled_kernel(float* __restrict__ p) {
    const int i = blockIdx.x * 256 + threadIdx.x;
    if (i < 768) p[i] = 0.f;
}

__global__ void final_kernel(const float* __restrict__ pooled, const float* __restrict__ Wd,
                             const float* __restrict__ bd, float* __restrict__ outp) {
    __shared__ float s_ss[256], s_dot[256];
    const int t = threadIdx.x;
    float ss = 0.f, dot = 0.f;
    for (int c = t; c < 768; c += 256) {
        const float v = pooled[c];
        ss  = fmaf(v, v, ss);
        dot = fmaf(v, Wd[c], dot);
    }
    s_ss[t] = ss; s_dot[t] = dot;
    __syncthreads();
    for (int off = 128; off > 0; off >>= 1) {
        if (t < off) { s_ss[t] += s_ss[t + off]; s_dot[t] += s_dot[t + off]; }
        __syncthreads();
    }
    if (t == 0) {
        const float norm = fmaxf(sqrtf(s_ss[0]), 1e-12f);
        outp[0] = s_dot[0] / norm + bd[0];
    }
}

extern "C" void kernel_launch(void* const* d_in, const int* in_sizes, int n_in,
                              void* d_out, int out_size, void* d_ws, size_t ws_size,
                              hipStream_t stream) {
    const float* x_int = (const float*)d_in[0];
    const float* x_nh  = (const float*)d_in[1];
    const int*   ei_int = (const int*)d_in[2];
    const int*   ei_nh  = (const int*)d_in[3];
    const float* W1  = (const float*)d_in[4];
    const float* a1s = (const float*)d_in[5];
    const float* a1d = (const float*)d_in[6];
    const float* W2  = (const float*)d_in[7];
    const float* a2s = (const float*)d_in[8];
    const float* a2d = (const float*)d_in[9];
    const float* W3  = (const float*)d_in[10];
    const float* a3s = (const float*)d_in[11];
    const float* a3d = (const float*)d_in[12];
    const float* Wd  = (const float*)d_in[13];
    const float* bd  = (const float*)d_in[14];
    float* out = (float*)d_out;

    // workspace layout (16B-aligned sections)
    unsigned short* hbf_a = (unsigned short*)d_ws;                 // NN2*96  bf16
    unsigned short* hbf_b = hbf_a + (size_t)NN2 * 96;              // NN2*192 bf16
    unsigned short* wt2   = hbf_b + (size_t)NN2 * 192;             // 192*96
    unsigned short* wt3   = wt2   + (size_t)96 * 192;              // 384*192
    unsigned* zf8 = (unsigned*)(wt3 + (size_t)192 * 384);          // NN2*96 dwords (fp8)
    float* es_t  = (float*)(zf8 + (size_t)NN2 * 96);               // H*NN2 (transposed)
    float* ed_t  = es_t + (size_t)HEADS * NN2;                     // H*NN2
    float* pooled = ed_t + (size_t)HEADS * NN2;                    // 768
    int* cnt     = (int*)(pooled + 768);                           // NN2
    int* part    = cnt + NN2;                                      // SCAN_NB*1024
    int* bsum    = part + SCAN_NB * 1024;                          // SCAN_NB
    int* boff    = bsum + SCAN_NB;                                 // SCAN_NB+1
    int* off     = boff + SCAN_NB + 1;                             // NN2+1
    int* cursor  = off + NN2 + 1;                                  // NN2
    unsigned short* csr16 = (unsigned short*)(cursor + NN2);       // NE2 u16
    unsigned char* zf8b = (unsigned char*)zf8;

    zero_pooled_kernel<<<3, 256, 0, stream>>>(pooled);
    convert_wt_kernel<<<(96 * 192 + 255) / 256, 256, 0, stream>>>(W2, wt2, 96, 192);
    convert_wt_kernel<<<(192 * 384 + 255) / 256, 256, 0, stream>>>(W3, wt3, 192, 384);

    // batched CSR over both graphs
    zero_int_kernel<<<(NN2 + 255) / 256, 256, 0, stream>>>(cnt, NN2);
    hist2_kernel<<<(NE2 + 255) / 256, 256, 0, stream>>>(ei_int, ei_nh, cnt);
    scan1_kernel<<<SCAN_NB, 1024, 0, stream>>>(cnt, part, bsum);
    scan2_kernel<<<1, 64, 0, stream>>>(bsum, boff);
    scan3_kernel<<<SCAN_NB, 1024, 0, stream>>>(part, boff, off, cursor);
    scatter2_kernel<<<(NE2 + 255) / 256, 256, 0, stream>>>(ei_int, ei_nh, cursor, csr16);

    const int mfma_blocks = (NN2 / 16 + 3) / 4;

    // layer 1: VALU GEMM + fused es/ed + fp8 z; agg GS=16, L=2, EPI=8
    gemm1_es_kernel<<<dim3(NN2 / 16, 2), 64, 0, stream>>>(x_int, x_nh, W1, a1s, a1d, zf8b,
                                                          es_t, ed_t);
    agg_sub_kernel<96, 16, 2812, 2814><<<8 * 2814, 256, 0, stream>>>(off, csr16, es_t, ed_t,
                                                                     zf8, hbf_a);
    // layer 2: MFMA GEMM + fused epilogue; agg GS=32, L=4, EPI=8
    gemm_es_kernel<96, 192><<<mfma_blocks, 256, 0, stream>>>(hbf_a, wt2, a2s, a2d, zf8b,
                                                             es_t, ed_t);
    agg_sub_kernel<192, 32, 5625, 5625><<<45000, 256, 0, stream>>>(off, csr16, es_t, ed_t,
                                                                   zf8, hbf_b);
    // layer 3: MFMA GEMM + fused epilogue, then agg+pool (L=8, EPI=8)
    gemm_es_kernel<192, 384><<<mfma_blocks, 256, 0, stream>>>(hbf_b, wt3, a3s, a3d, zf8b,
                                                              es_t, ed_t);
    agg_pool_kernel<<<POOL_BLOCKS, 256, 0, stream>>>(off, csr16, es_t, ed_t, zf8, pooled);

    final_kernel<<<1, 256, 0, stream>>>(pooled, Wd, bd, out);
}

// Round 19
// 616.375 us; speedup vs baseline: 1.1497x; 1.1497x over previous
//
#include <hip/hip_runtime.h>
#include <math.h>

#define N_NODES 30000
#define N_EDGES 480000
#define HEADS   6
#define NN2 (2 * N_NODES)
#define NE2 (2 * N_EDGES)

typedef __attribute__((ext_vector_type(8))) short bf16x8;
typedef __attribute__((ext_vector_type(4))) float f32x4;
typedef __attribute__((ext_vector_type(2))) float f32x2;

// ---------- bf16 helper (agg outputs feeding next GEMM's A-operand) ----------
__device__ __forceinline__ unsigned short f2bf(float f) {
    unsigned u = __float_as_uint(f);
    u += 0x7fffu + ((u >> 16) & 1u);   // RNE
    return (unsigned short)(u >> 16);
}

// ---------- layer-1 GEMM (K=11, VALU) fused with es/ed + fp8-z epilogue ----------
__global__ void gemm1_es_kernel(const float* __restrict__ x0, const float* __restrict__ x1,
                                const float* __restrict__ W, const float* __restrict__ a_s,
                                const float* __restrict__ a_d,
                                unsigned char* __restrict__ zf8b, float* __restrict__ es_t,
                                float* __restrict__ ed_t) {
    constexpr int K = 11, HF = 96, TM = 16;
    __shared__ float hs[TM * K];
    const int m0 = blockIdx.x * TM;
    const float* h = (m0 < N_NODES) ? (x0 + (size_t)m0 * K)
                                    : (x1 + (size_t)(m0 - N_NODES) * K);
    const int j = blockIdx.y * 64 + threadIdx.x;
    for (int idx = threadIdx.x; idx < TM * K; idx += 64) hs[idx] = h[idx];
    __syncthreads();
    if (j >= HF) return;
    float acc[TM];
#pragma unroll
    for (int m = 0; m < TM; ++m) acc[m] = 0.f;
    for (int k = 0; k < K; ++k) {
        float w = W[k * HF + j];
#pragma unroll
        for (int m = 0; m < TM; ++m) acc[m] = fmaf(hs[m * K + k], w, acc[m]);
    }
    const float as_v = a_s[j];
    const float ad_v = a_d[j];
    const int hh = j >> 4;          // head = col/16 (Fo=16)
#pragma unroll
    for (int m = 0; m < TM; ++m) {
        const int pk = __builtin_amdgcn_cvt_pk_fp8_f32(acc[m], acc[m], 0, false);
        zf8b[(size_t)(m0 + m) * HF + j] = (unsigned char)pk;
    }
#pragma unroll
    for (int m = 0; m < TM; ++m) {
        float ep = acc[m] * as_v;
        float dp = acc[m] * ad_v;
#pragma unroll
        for (int d = 1; d < 16; d <<= 1) {
            ep += __shfl_xor(ep, d);
            dp += __shfl_xor(dp, d);
        }
        if ((threadIdx.x & 15) == 0) {
            es_t[(size_t)hh * NN2 + m0 + m] = ep;
            ed_t[(size_t)hh * NN2 + m0 + m] = dp;
        }
    }
}

// ---------- W -> Wt (transposed, bf16) ----------
__global__ void convert_wt_kernel(const float* __restrict__ W, unsigned short* __restrict__ Wt,
                                  int K, int HF) {
    const int idx = blockIdx.x * 256 + threadIdx.x;
    if (idx >= K * HF) return;
    const int k = idx / HF;
    const int n = idx - k * HF;
    Wt[n * K + k] = f2bf(W[idx]);
}

// ---------- MFMA GEMM fused with es/ed + fp8-z epilogue ----------
template <int K, int HF>
__global__ __launch_bounds__(256) void gemm_es_kernel(
        const unsigned short* __restrict__ hbf, const unsigned short* __restrict__ Wt,
        const float* __restrict__ a_s, const float* __restrict__ a_d,
        unsigned char* __restrict__ zf8b, float* __restrict__ es_t,
        float* __restrict__ ed_t) {
    constexpr int KSTEPS = K / 32;
    constexpr int Fo  = HF / HEADS;
    constexpr int TPH = Fo / 16;        // tiles per head
    const int wid = blockIdx.x * 4 + (threadIdx.x >> 6);
    if (wid >= NN2 / 16) return;
    const int lane = threadIdx.x & 63;
    const int r16  = lane & 15;
    const int quad = lane >> 4;
    const int m0 = wid * 16;

    bf16x8 afrag[KSTEPS];
    const unsigned short* ap = hbf + (size_t)(m0 + r16) * K + quad * 8;
#pragma unroll
    for (int i = 0; i < KSTEPS; ++i) afrag[i] = *(const bf16x8*)(ap + i * 32);

    const unsigned short* bp = Wt + (size_t)r16 * K + quad * 8;
    float es_p[4] = {0.f, 0.f, 0.f, 0.f};
    float ed_p[4] = {0.f, 0.f, 0.f, 0.f};
    for (int t = 0; t < HF / 16; ++t) {
        f32x4 acc = {0.f, 0.f, 0.f, 0.f};
        const unsigned short* bpt = bp + (size_t)t * 16 * K;
#pragma unroll
        for (int i = 0; i < KSTEPS; ++i) {
            const bf16x8 bfrag = *(const bf16x8*)(bpt + i * 32);
            acc = __builtin_amdgcn_mfma_f32_16x16x32_bf16(afrag[i], bfrag, acc, 0, 0, 0);
        }
        const float as_v = a_s[t * 16 + r16];
        const float ad_v = a_d[t * 16 + r16];
        unsigned char* zp = zf8b + (size_t)(m0 + quad * 4) * HF + t * 16 + r16;
#pragma unroll
        for (int r = 0; r < 4; ++r) {
            const int pk = __builtin_amdgcn_cvt_pk_fp8_f32(acc[r], acc[r], 0, false);
            zp[(size_t)r * HF] = (unsigned char)pk;
            es_p[r] = fmaf(acc[r], as_v, es_p[r]);
            ed_p[r] = fmaf(acc[r], ad_v, ed_p[r]);
        }
        if (((t + 1) % TPH) == 0) {     // head boundary: reduce + store + reset
            const int h = t / TPH;
#pragma unroll
            for (int r = 0; r < 4; ++r) {
                float ep = es_p[r], dp = ed_p[r];
#pragma unroll
                for (int d = 1; d < 16; d <<= 1) {
                    ep += __shfl_xor(ep, d);
                    dp += __shfl_xor(dp, d);
                }
                if (r16 == 0) {
                    es_t[(size_t)h * NN2 + m0 + quad * 4 + r] = ep;
                    ed_t[(size_t)h * NN2 + m0 + quad * 4 + r] = dp;
                }
                es_p[r] = 0.f;
                ed_p[r] = 0.f;
            }
        }
    }
}

// ---------- CSR build (both graphs, global node ids; src stored as u16) ----------
__global__ void zero_int_kernel(int* __restrict__ p, int n) {
    const int i = blockIdx.x * 256 + threadIdx.x;
    if (i < n) p[i] = 0;
}

__global__ void hist2_kernel(const int* __restrict__ ei0, const int* __restrict__ ei1,
                             int* __restrict__ cnt) {
    const int e = blockIdx.x * 256 + threadIdx.x;
    if (e >= NE2) return;
    const int g = e >= N_EDGES;
    const int* ei = g ? ei1 : ei0;
    const int e2 = e - g * N_EDGES;
    atomicAdd(&cnt[g * N_NODES + ei[N_EDGES + e2]], 1);
}

#define SCAN_NB ((NN2 + 1023) / 1024)
__global__ void scan1_kernel(const int* __restrict__ cnt, int* __restrict__ part,
                             int* __restrict__ bsum) {
    __shared__ int s[1024];
    const int t = threadIdx.x;
    const int gid = blockIdx.x * 1024 + t;
    const int v = (gid < NN2) ? cnt[gid] : 0;
    s[t] = v;
    __syncthreads();
    for (int d = 1; d < 1024; d <<= 1) {
        int x = (t >= d) ? s[t - d] : 0;
        __syncthreads();
        s[t] += x;
        __syncthreads();
    }
    part[gid] = s[t] - v;
    if (t == 1023) bsum[blockIdx.x] = s[1023];
}

__global__ void scan2_kernel(int* __restrict__ bsum, int* __restrict__ boff) {
    if (threadIdx.x == 0) {
        int a = 0;
        for (int i = 0; i < SCAN_NB; ++i) { boff[i] = a; a += bsum[i]; }
        boff[SCAN_NB] = a;
    }
}

__global__ void scan3_kernel(const int* __restrict__ part, const int* __restrict__ boff,
                             int* __restrict__ off, int* __restrict__ cursor) {
    const int gid = blockIdx.x * 1024 + threadIdx.x;
    if (gid < NN2) {
        const int o = part[gid] + boff[gid >> 10];
        off[gid] = o;
        cursor[gid] = o;
    }
    if (gid == 0) off[NN2] = boff[SCAN_NB];
}

__global__ void scatter2_kernel(const int* __restrict__ ei0, const int* __restrict__ ei1,
                                int* __restrict__ cursor,
                                unsigned short* __restrict__ csr16) {
    const int e = blockIdx.x * 256 + threadIdx.x;
    if (e >= NE2) return;
    const int g = e >= N_EDGES;
    const int* ei = g ? ei1 : ei0;
    const int e2 = e - g * N_EDGES;
    const int src = g * N_NODES + ei[e2];           // < 60000, fits u16
    const int dst = g * N_NODES + ei[N_EDGES + e2];
    const int slot = atomicAdd(&cursor[dst], 1);
    csr16[slot] = (unsigned short)src;
}

// ---------- layer aggs: sub-wave node-head groups (R17, proven) ----------
// GS lanes own one (node, head): L=Fo/4 feat-lanes x EPI=GS/L edges in flight (EPI=4).
// Reduction: log2(EPI) shfl steps within the GS-group. Nodes sequential (R13 lesson).
// XCD-affine head swizzle with EXACT coverage: r<6 -> h=r, blk=g (g<MAIN);
// r in {6,7} -> k=(r-6)*G+g, h=k%6, blk=MAIN+k/6. Grid = 8*G.
template <int HF, int GS, int MAIN, int G>
__global__ __launch_bounds__(256) void agg_sub_kernel(
        const int* __restrict__ off, const unsigned short* __restrict__ csr16,
        const float* __restrict__ es_t, const float* __restrict__ ed_t,
        const unsigned* __restrict__ zf8, unsigned short* __restrict__ outz) {
    constexpr int Fo  = HF / HEADS;
    constexpr int L   = Fo / 4;          // feat-dword lanes per edge
    constexpr int EPI = GS / L;          // edges in parallel (4)
    constexpr int GPW = 64 / GS;         // node-heads per wave
    constexpr int NB  = 4 * GPW;         // node-heads per block
    constexpr int BPH = NN2 / NB;        // blocks per head
    int h, blk;
    {
        const int r = blockIdx.x & 7, g = blockIdx.x >> 3;
        if (r < 6) {
            if (g >= MAIN) return;
            h = r; blk = g;
        } else {
            const int k = (r - 6) * G + g;
            if (k >= 6 * (BPH - MAIN)) return;
            h = k % 6; blk = MAIN + k / 6;
        }
    }
    const int wavid = threadIdx.x >> 6;
    const int lane  = threadIdx.x & 63;
    const int grp = lane / GS;           // node-head group within wave
    const int lg  = lane - grp * GS;
    const int eo = lg / L;
    const int fp = lg - eo * L;
    const int n = blk * NB + wavid * GPW + grp;

    const int s0  = off[n];
    const int deg = off[n + 1] - s0;
    const float edn = ed_t[(size_t)h * NN2 + n];
    const float* esh = es_t + (size_t)h * NN2;

    float a0 = 0.f, a1 = 0.f, a2 = 0.f, a3 = 0.f, lsum = 0.f;
#pragma unroll 4
    for (int i = eo; i < deg; i += EPI) {
        const int src = (int)csr16[s0 + i];
        float v = esh[src] + edn;
        v = fmaxf(v, 0.2f * v);
        const float ww = __expf(v);
        lsum += ww;
        const unsigned zz = zf8[(size_t)src * (HF / 4) + h * (Fo / 4) + fp];
        const f32x2 lo = __builtin_amdgcn_cvt_pk_f32_fp8((int)zz, false);
        const f32x2 hi = __builtin_amdgcn_cvt_pk_f32_fp8((int)zz, true);
        a0 = fmaf(ww, lo.x, a0);
        a1 = fmaf(ww, lo.y, a1);
        a2 = fmaf(ww, hi.x, a2);
        a3 = fmaf(ww, hi.y, a3);
    }
#pragma unroll
    for (int d = L; d < GS; d <<= 1) {   // reduce within GS-group only
        a0 += __shfl_xor(a0, d);
        a1 += __shfl_xor(a1, d);
        a2 += __shfl_xor(a2, d);
        a3 += __shfl_xor(a3, d);
        lsum += __shfl_xor(lsum, d);
    }
    if (eo == 0) {
        const float inv = 1.f / (lsum + 1e-16f);
        float o0 = a0 * inv, o1 = a1 * inv, o2 = a2 * inv, o3 = a3 * inv;
        o0 = o0 > 0.f ? o0 : expm1f(o0);
        o1 = o1 > 0.f ? o1 : expm1f(o1);
        o2 = o2 > 0.f ? o2 : expm1f(o2);
        o3 = o3 > 0.f ? o3 : expm1f(o3);
        unsigned short* op = outz + (size_t)n * HF + h * Fo + 4 * fp;
        *(unsigned*)op       = (unsigned)f2bf(o0) | ((unsigned)f2bf(o1) << 16);
        *(unsigned*)(op + 2) = (unsigned)f2bf(o2) | ((unsigned)f2bf(o3) << 16);
    }
}

// ---------- layer-3 aggregation fused with sum pooling (R12/R15/R17-proven) ----------
#define POOL_BLOCKS 3072
#define POOL_WPH 2048
__global__ __launch_bounds__(256) void agg_pool_kernel(
        const int* __restrict__ off, const unsigned short* __restrict__ csr16,
        const float* __restrict__ es_t, const float* __restrict__ ed_t,
        const unsigned* __restrict__ zf8, float* __restrict__ pooled) {
    constexpr int HF = 384, Fo = 64, L = 16, EPI = 4;
    __shared__ float lds[128];
    int h, slot;
    {
        const int r = blockIdx.x & 7, g = blockIdx.x >> 3;   // g in [0,384)
        if (r < 6) { h = r; slot = g; }
        else { h = g % 6; slot = 384 + (r - 6) * 64 + g / 6; }
    }
    const int wavid = threadIdx.x >> 6;
    const int ws    = slot * 4 + wavid;
    const int lane  = threadIdx.x & 63;
    const int eo = lane / L;
    const int fp = lane - eo * L;
    const float* esh = es_t + (size_t)h * NN2;
    const float* edh = ed_t + (size_t)h * NN2;

    if (threadIdx.x < 128) lds[threadIdx.x] = 0.f;
    __syncthreads();

    float p0[4] = {0.f, 0.f, 0.f, 0.f};
    float p1[4] = {0.f, 0.f, 0.f, 0.f};
    for (int n = ws; n < NN2; n += POOL_WPH) {
        const int s0  = off[n];
        const int deg = off[n + 1] - s0;
        const float edn = edh[n];
        float a0 = 0.f, a1 = 0.f, a2 = 0.f, a3 = 0.f, lsum = 0.f;
#pragma unroll 4
        for (int i = eo; i < deg; i += EPI) {
            const int src = (int)csr16[s0 + i];
            float v = esh[src] + edn;
            v = fmaxf(v, 0.2f * v);
            const float ww = __expf(v);
            lsum += ww;
            const unsigned zz = zf8[(size_t)src * (HF / 4) + h * (Fo / 4) + fp];
            const f32x2 lo = __builtin_amdgcn_cvt_pk_f32_fp8((int)zz, false);
            const f32x2 hi = __builtin_amdgcn_cvt_pk_f32_fp8((int)zz, true);
            a0 = fmaf(ww, lo.x, a0);
            a1 = fmaf(ww, lo.y, a1);
            a2 = fmaf(ww, hi.x, a2);
            a3 = fmaf(ww, hi.y, a3);
        }
#pragma unroll
        for (int d = L; d < 64; d <<= 1) {
            a0 += __shfl_xor(a0, d);
            a1 += __shfl_xor(a1, d);
            a2 += __shfl_xor(a2, d);
            a3 += __shfl_xor(a3, d);
            lsum += __shfl_xor(lsum, d);
        }
        if (eo == 0) {
            const float inv = 1.f / (lsum + 1e-16f);
            float o0 = a0 * inv, o1 = a1 * inv, o2 = a2 * inv, o3 = a3 * inv;
            o0 = o0 > 0.f ? o0 : expm1f(o0);
            o1 = o1 > 0.f ? o1 : expm1f(o1);
            o2 = o2 > 0.f ? o2 : expm1f(o2);
            o3 = o3 > 0.f ? o3 : expm1f(o3);
            if (n < N_NODES) { p0[0] += o0; p0[1] += o1; p0[2] += o2; p0[3] += o3; }
            else             { p1[0] += o0; p1[1] += o1; p1[2] += o2; p1[3] += o3; }
        }
    }
    if (eo == 0) {
#pragma unroll
        for (int j = 0; j < 4; ++j) {
            atomicAdd(&lds[4 * fp + j], p0[j]);
            atomicAdd(&lds[64 + 4 * fp + j], p1[j]);
        }
    }
    __syncthreads();
    if (threadIdx.x < 128) {
        const int g2 = threadIdx.x >> 6;
        const int f  = threadIdx.x & 63;
        atomicAdd(&pooled[g2 * 384 + h * Fo + f], lds[threadIdx.x]);
    }
}

__global__ void zero_pooled_kernel(float* __restrict__ p) {
    const int i = blockIdx.x * 256 + threadIdx.x;
    if (i < 768) p[i] = 0.f;
}

__global__ void final_kernel(const float* __restrict__ pooled, const float* __restrict__ Wd,
                             const float* __restrict__ bd, float* __restrict__ outp) {
    __shared__ float s_ss[256], s_dot[256];
    const int t = threadIdx.x;
    float ss = 0.f, dot = 0.f;
    for (int c = t; c < 768; c += 256) {
        const float v = pooled[c];
        ss  = fmaf(v, v, ss);
        dot = fmaf(v, Wd[c], dot);
    }
    s_ss[t] = ss; s_dot[t] = dot;
    __syncthreads();
    for (int off = 128; off > 0; off >>= 1) {
        if (t < off) { s_ss[t] += s_ss[t + off]; s_dot[t] += s_dot[t + off]; }
        __syncthreads();
    }
    if (t == 0) {
        const float norm = fmaxf(sqrtf(s_ss[0]), 1e-12f);
        outp[0] = s_dot[0] / norm + bd[0];
    }
}

extern "C" void kernel_launch(void* const* d_in, const int* in_sizes, int n_in,
                              void* d_out, int out_size, void* d_ws, size_t ws_size,
                              hipStream_t stream) {
    const float* x_int = (const float*)d_in[0];
    const float* x_nh  = (const float*)d_in[1];
    const int*   ei_int = (const int*)d_in[2];
    const int*   ei_nh  = (const int*)d_in[3];
    const float* W1  = (const float*)d_in[4];
    const float* a1s = (const float*)d_in[5];
    const float* a1d = (const float*)d_in[6];
    const float* W2  = (const float*)d_in[7];
    const float* a2s = (const float*)d_in[8];
    const float* a2d = (const float*)d_in[9];
    const float* W3  = (const float*)d_in[10];
    const float* a3s = (const float*)d_in[11];
    const float* a3d = (const float*)d_in[12];
    const float* Wd  = (const float*)d_in[13];
    const float* bd  = (const float*)d_in[14];
    float* out = (float*)d_out;

    // workspace layout (16B-aligned sections)
    unsigned short* hbf_a = (unsigned short*)d_ws;                 // NN2*96  bf16
    unsigned short* hbf_b = hbf_a + (size_t)NN2 * 96;              // NN2*192 bf16
    unsigned short* wt2   = hbf_b + (size_t)NN2 * 192;             // 192*96
    unsigned short* wt3   = wt2   + (size_t)96 * 192;              // 384*192
    unsigned* zf8 = (unsigned*)(wt3 + (size_t)192 * 384);          // NN2*96 dwords (fp8)
    float* es_t  = (float*)(zf8 + (size_t)NN2 * 96);               // H*NN2 (transposed)
    float* ed_t  = es_t + (size_t)HEADS * NN2;                     // H*NN2
    float* pooled = ed_t + (size_t)HEADS * NN2;                    // 768
    int* cnt     = (int*)(pooled + 768);                           // NN2
    int* part    = cnt + NN2;                                      // SCAN_NB*1024
    int* bsum    = part + SCAN_NB * 1024;                          // SCAN_NB
    int* boff    = bsum + SCAN_NB;                                 // SCAN_NB+1
    int* off     = boff + SCAN_NB + 1;                             // NN2+1
    int* cursor  = off + NN2 + 1;                                  // NN2
    unsigned short* csr16 = (unsigned short*)(cursor + NN2);       // NE2 u16
    unsigned char* zf8b = (unsigned char*)zf8;

    zero_pooled_kernel<<<3, 256, 0, stream>>>(pooled);
    convert_wt_kernel<<<(96 * 192 + 255) / 256, 256, 0, stream>>>(W2, wt2, 96, 192);
    convert_wt_kernel<<<(192 * 384 + 255) / 256, 256, 0, stream>>>(W3, wt3, 192, 384);

    // batched CSR over both graphs
    zero_int_kernel<<<(NN2 + 255) / 256, 256, 0, stream>>>(cnt, NN2);
    hist2_kernel<<<(NE2 + 255) / 256, 256, 0, stream>>>(ei_int, ei_nh, cnt);
    scan1_kernel<<<SCAN_NB, 1024, 0, stream>>>(cnt, part, bsum);
    scan2_kernel<<<1, 64, 0, stream>>>(bsum, boff);
    scan3_kernel<<<SCAN_NB, 1024, 0, stream>>>(part, boff, off, cursor);
    scatter2_kernel<<<(NE2 + 255) / 256, 256, 0, stream>>>(ei_int, ei_nh, cursor, csr16);

    const int mfma_blocks = (NN2 / 16 + 3) / 4;

    // layer 1: VALU GEMM + fused es/ed + fp8 z; agg with GS=16 (4 node-heads/wave)
    gemm1_es_kernel<<<dim3(NN2 / 16, 2), 64, 0, stream>>>(x_int, x_nh, W1, a1s, a1d, zf8b,
                                                          es_t, ed_t);
    agg_sub_kernel<96, 16, 2812, 2814><<<8 * 2814, 256, 0, stream>>>(off, csr16, es_t, ed_t,
                                                                     zf8, hbf_a);
    // layer 2: MFMA GEMM + fused epilogue; agg with GS=32 (2 node-heads/wave)
    gemm_es_kernel<96, 192><<<mfma_blocks, 256, 0, stream>>>(hbf_a, wt2, a2s, a2d, zf8b,
                                                             es_t, ed_t);
    agg_sub_kernel<192, 32, 5625, 5625><<<45000, 256, 0, stream>>>(off, csr16, es_t, ed_t,
                                                                   zf8, hbf_b);
    // layer 3: MFMA GEMM + fused epilogue, then agg+pool (unchanged)
    gemm_es_kernel<192, 384><<<mfma_blocks, 256, 0, stream>>>(hbf_b, wt3, a3s, a3d, zf8b,
                                                              es_t, ed_t);
    agg_pool_kernel<<<POOL_BLOCKS, 256, 0, stream>>>(off, csr16, es_t, ed_t, zf8, pooled);

    final_kernel<<<1, 256, 0, stream>>>(pooled, Wd, bd, out);
}